// Round 2
// baseline (19388.434 us; speedup 1.0000x reference)
//
#include <hip/hip_runtime.h>

typedef float floatx4 __attribute__((ext_vector_type(4)));
typedef short shortx8 __attribute__((ext_vector_type(8)));

__device__ __forceinline__ float bf16_to_f(unsigned short u) {
    union { unsigned int i; float f; } v;
    v.i = ((unsigned int)u) << 16;
    return v.f;
}
__device__ __forceinline__ unsigned short f_to_bf16(float f) {
    union { float f; unsigned int i; } v;
    v.f = f;
    unsigned int lsb = (v.i >> 16) & 1u;
    unsigned int r = v.i + 0x7fffu + lsb;
    return (unsigned short)(r >> 16);
}

// ---------------- count / invcnt ----------------
__global__ __launch_bounds__(256) void k_count(const int* __restrict__ dst,
                                               float* __restrict__ cnt, int E) {
    int e = blockIdx.x * 256 + threadIdx.x;
    if (e < E) atomicAdd(&cnt[dst[e]], 1.0f);
}

__global__ __launch_bounds__(256) void k_invcnt(const float* __restrict__ cnt,
                                                float* __restrict__ inv, int n) {
    int i = blockIdx.x * 256 + threadIdx.x;
    if (i < n) inv[i] = 1.0f / fmaxf(cnt[i], 1.0f);
}

// ---------------- scatter: acc[dst] += x[src] (fp32 source) ----------------
// 4 edges per wave, 16 lanes per edge, 8 columns (32B) per lane.
__global__ __launch_bounds__(256) void k_scatter_f32(const float* __restrict__ x,
                                                     const int* __restrict__ src,
                                                     const int* __restrict__ dst,
                                                     float* __restrict__ acc, int E) {
    int w = blockIdx.x * 4 + (threadIdx.x >> 6);
    int lane = threadIdx.x & 63;
    int e = w * 4 + (lane >> 4);
    if (e >= E) return;
    int s = src[e];
    int d = dst[e];
    int c0 = (lane & 15) << 3;
    const floatx4* xp = (const floatx4*)(x + ((size_t)s << 7) + c0);
    floatx4 v0 = xp[0];
    floatx4 v1 = xp[1];
    float* ap = acc + ((size_t)d << 7) + c0;
    atomicAdd(ap + 0, v0[0]);
    atomicAdd(ap + 1, v0[1]);
    atomicAdd(ap + 2, v0[2]);
    atomicAdd(ap + 3, v0[3]);
    atomicAdd(ap + 4, v1[0]);
    atomicAdd(ap + 5, v1[1]);
    atomicAdd(ap + 6, v1[2]);
    atomicAdd(ap + 7, v1[3]);
}

// ---------------- scatter: acc[dst] += x[src] (bf16 source) ----------------
__global__ __launch_bounds__(256) void k_scatter_bf16(const unsigned short* __restrict__ x,
                                                      const int* __restrict__ src,
                                                      const int* __restrict__ dst,
                                                      float* __restrict__ acc, int E) {
    int w = blockIdx.x * 4 + (threadIdx.x >> 6);
    int lane = threadIdx.x & 63;
    int e = w * 4 + (lane >> 4);
    if (e >= E) return;
    int s = src[e];
    int d = dst[e];
    int c0 = (lane & 15) << 3;
    const uint4* xp = (const uint4*)(x + ((size_t)s << 7) + c0);
    uint4 pk = *xp;
    float* ap = acc + ((size_t)d << 7) + c0;
    atomicAdd(ap + 0, bf16_to_f((unsigned short)(pk.x & 0xffffu)));
    atomicAdd(ap + 1, bf16_to_f((unsigned short)(pk.x >> 16)));
    atomicAdd(ap + 2, bf16_to_f((unsigned short)(pk.y & 0xffffu)));
    atomicAdd(ap + 3, bf16_to_f((unsigned short)(pk.y >> 16)));
    atomicAdd(ap + 4, bf16_to_f((unsigned short)(pk.z & 0xffffu)));
    atomicAdd(ap + 5, bf16_to_f((unsigned short)(pk.z >> 16)));
    atomicAdd(ap + 6, bf16_to_f((unsigned short)(pk.w & 0xffffu)));
    atomicAdd(ap + 7, bf16_to_f((unsigned short)(pk.w >> 16)));
}

// ---------------- build stacked weights per layer (fp32 in, bf16 out) ---------
// Wt layouts (bf16, [128 n x K k] row-major):
//  gene  K=512: [Wl(e0) | Wl(e3) | Wl(e4) | Wr(e0)+Wr(e3)+Wr(e4)]
//  drug  K=256: [Wl(e1) | Wr(e1)]
//  dis   K=256: [Wl(e2) | Wr(e2)]
__global__ __launch_bounds__(256) void k_build_w(const float* __restrict__ Wl,
                                                 const float* __restrict__ Wr,
                                                 const float* __restrict__ bl,
                                                 int l,
                                                 unsigned short* __restrict__ Wg,
                                                 unsigned short* __restrict__ Wd,
                                                 unsigned short* __restrict__ Ws,
                                                 float* __restrict__ bg,
                                                 float* __restrict__ bd,
                                                 float* __restrict__ bs) {
    int t = blockIdx.x * 256 + threadIdx.x;
    // Wl/Wr: [2][5][128][128] fp32
    if (t < 128 * 512) {
        int n = t >> 9;
        int kg = t & 511;
        int b = kg >> 7, k = kg & 127;
        float v;
        if (b == 0)
            v = Wl[(((size_t)l * 5 + 0) * 128 + n) * 128 + k];
        else if (b == 1)
            v = Wl[(((size_t)l * 5 + 3) * 128 + n) * 128 + k];
        else if (b == 2)
            v = Wl[(((size_t)l * 5 + 4) * 128 + n) * 128 + k];
        else
            v = Wr[(((size_t)l * 5 + 0) * 128 + n) * 128 + k] +
                Wr[(((size_t)l * 5 + 3) * 128 + n) * 128 + k] +
                Wr[(((size_t)l * 5 + 4) * 128 + n) * 128 + k];
        Wg[n * 512 + kg] = f_to_bf16(v);
    } else if (t < 131072) {
        int t2 = t - 65536;
        int which = (t2 >= 32768) ? 1 : 0;  // 0=drug(e1), 1=disease(e2)
        int t3 = which ? t2 - 32768 : t2;
        int n = t3 >> 8;
        int kg = t3 & 255;
        int b = kg >> 7, k = kg & 127;
        int ei = which ? 2 : 1;
        float v = (b == 0) ? Wl[(((size_t)l * 5 + ei) * 128 + n) * 128 + k]
                           : Wr[(((size_t)l * 5 + ei) * 128 + n) * 128 + k];
        (which ? Ws : Wd)[n * 256 + kg] = f_to_bf16(v);
    }
    if (t < 128) {
        int n = t;
        bg[n] = bl[((size_t)l * 5 + 0) * 128 + n] +
                bl[((size_t)l * 5 + 3) * 128 + n] +
                bl[((size_t)l * 5 + 4) * 128 + n];
        bd[n] = bl[((size_t)l * 5 + 1) * 128 + n];
        bs[n] = bl[((size_t)l * 5 + 2) * 128 + n];
    }
}

// ---------------- fused GEMM ----------------
// out[M,128] = relu( ( [mean_0|mean_1|mean_2|x] @ Wt^T + bias_sum ) * inv_k )
// block = 256 = 4 waves; each wave: 16 rows x 128 cols via 8 MFMA 16x16x32 tiles.
// XBF: x operand is bf16 (else fp32). OUTBF: write bf16 (else fp32).
template <bool XBF, bool OUTBF>
__global__ __launch_bounds__(256) void k_gemm(const float* __restrict__ a0, const float* __restrict__ i0,
                                              const float* __restrict__ a1, const float* __restrict__ i1,
                                              const float* __restrict__ a2, const float* __restrict__ i2,
                                              int n_acc,
                                              const void* __restrict__ xdst,
                                              const unsigned short* __restrict__ Wt,
                                              const float* __restrict__ bias,
                                              float inv_k,
                                              void* __restrict__ out,
                                              int M) {
    const int K = (n_acc + 1) << 7;
    const int lane = threadIdx.x & 63;
    const int wave = threadIdx.x >> 6;
    const int quad = lane >> 4;
    const int l16 = lane & 15;
    const int m_base = blockIdx.x * 64 + wave * 16;
    int row = m_base + l16;
    if (row > M - 1) row = M - 1;

    floatx4 acc[8];
#pragma unroll
    for (int i = 0; i < 8; i++) acc[i] = floatx4{0.f, 0.f, 0.f, 0.f};

    for (int s = 0; s <= n_acc; s++) {
        const bool is_x = (s == n_acc);
        const float* ap = nullptr;
        float ic = 0.f;
        if (!is_x) {
            const float* accp = (s == 0) ? a0 : (s == 1) ? a1 : a2;
            const float* icp = (s == 0) ? i0 : (s == 1) ? i1 : i2;
            ap = accp + ((size_t)row << 7);
            ic = icp[row];
        }
#pragma unroll
        for (int kq = 0; kq < 4; kq++) {
            const int ko = (kq << 5) + (quad << 3);  // k offset within 128-block
            shortx8 afrag;
            if (!is_x) {
                floatx4 v0 = *(const floatx4*)(ap + ko);
                floatx4 v1 = *(const floatx4*)(ap + ko + 4);
                afrag[0] = (short)f_to_bf16(v0[0] * ic);
                afrag[1] = (short)f_to_bf16(v0[1] * ic);
                afrag[2] = (short)f_to_bf16(v0[2] * ic);
                afrag[3] = (short)f_to_bf16(v0[3] * ic);
                afrag[4] = (short)f_to_bf16(v1[0] * ic);
                afrag[5] = (short)f_to_bf16(v1[1] * ic);
                afrag[6] = (short)f_to_bf16(v1[2] * ic);
                afrag[7] = (short)f_to_bf16(v1[3] * ic);
            } else if (XBF) {
                const unsigned short* xp = (const unsigned short*)xdst + ((size_t)row << 7);
                afrag = *(const shortx8*)(xp + ko);
            } else {
                const float* xp = (const float*)xdst + ((size_t)row << 7);
                floatx4 v0 = *(const floatx4*)(xp + ko);
                floatx4 v1 = *(const floatx4*)(xp + ko + 4);
                afrag[0] = (short)f_to_bf16(v0[0]);
                afrag[1] = (short)f_to_bf16(v0[1]);
                afrag[2] = (short)f_to_bf16(v0[2]);
                afrag[3] = (short)f_to_bf16(v0[3]);
                afrag[4] = (short)f_to_bf16(v1[0]);
                afrag[5] = (short)f_to_bf16(v1[1]);
                afrag[6] = (short)f_to_bf16(v1[2]);
                afrag[7] = (short)f_to_bf16(v1[3]);
            }
            const int kglob = (s << 7) + ko;
            const unsigned short* wp = Wt + (size_t)l16 * K + kglob;
#pragma unroll
            for (int nt = 0; nt < 8; nt++) {
                shortx8 bfrag = *(const shortx8*)(wp + ((size_t)(nt << 4)) * K);
                acc[nt] = __builtin_amdgcn_mfma_f32_16x16x32_bf16(afrag, bfrag, acc[nt], 0, 0, 0);
            }
        }
    }

    // epilogue: D mapping col=lane&15, row=quad*4+reg
#pragma unroll
    for (int nt = 0; nt < 8; nt++) {
        const int col = (nt << 4) + l16;
        const float b = bias[col];
#pragma unroll
        for (int r = 0; r < 4; r++) {
            const int orow = m_base + (quad << 2) + r;
            if (orow < M) {
                float v = fmaxf((acc[nt][r] + b) * inv_k, 0.f);
                if (OUTBF)
                    ((unsigned short*)out)[((size_t)orow << 7) + col] = f_to_bf16(v);
                else
                    ((float*)out)[((size_t)orow << 7) + col] = v;
            }
        }
    }
}

extern "C" void kernel_launch(void* const* d_in, const int* in_sizes, int n_in,
                              void* d_out, int out_size, void* d_ws, size_t ws_size,
                              hipStream_t stream) {
    const float* emb_drug = (const float*)d_in[0];
    const float* emb_dis  = (const float*)d_in[1];
    const float* emb_gene = (const float*)d_in[2];
    const float* Wl = (const float*)d_in[3];
    const float* Wr = (const float*)d_in[4];
    const float* bl = (const float*)d_in[5];
    const int* es[5] = {(const int*)d_in[6], (const int*)d_in[8], (const int*)d_in[10],
                        (const int*)d_in[12], (const int*)d_in[14]};
    const int* ed[5] = {(const int*)d_in[7], (const int*)d_in[9], (const int*)d_in[11],
                        (const int*)d_in[13], (const int*)d_in[15]};
    const int E[5] = {640000, 640000, 320000, 320000, 800000};
    const int ndst[5] = {50000, 20000, 10000, 50000, 50000};  // gene,drug,dis,gene,gene
    long long cnt_off[5], acc_off[5];
    {
        long long o = 0;
        for (int t = 0; t < 5; t++) { cnt_off[t] = o; acc_off[t] = o * 128; o += ndst[t]; }
    }

    char* base = (char*)d_ws;
    size_t off = 0;
    auto alloc = [&](size_t bytes) -> void* {
        void* r = base + off;
        off = (off + bytes + 255) & ~(size_t)255;
        return r;
    };
    const size_t ACC_BYTES = 180000ull * 128 * 4;
    float* acc = (float*)alloc(ACC_BYTES);
    float* cnt = (float*)alloc(180000ull * 4);
    float* inv = (float*)alloc(180000ull * 4);
    unsigned short* x1_drug = (unsigned short*)alloc(20000ull * 128 * 2);
    unsigned short* x1_dis  = (unsigned short*)alloc(10000ull * 128 * 2);
    unsigned short* x1_gene = (unsigned short*)alloc(50000ull * 128 * 2);
    unsigned short* Wg = (unsigned short*)alloc(128ull * 512 * 2);
    unsigned short* Wd = (unsigned short*)alloc(128ull * 256 * 2);
    unsigned short* Ws = (unsigned short*)alloc(128ull * 256 * 2);
    float* bg = (float*)alloc(128 * 4);
    float* bd = (float*)alloc(128 * 4);
    float* bs = (float*)alloc(128 * 4);

    hipMemsetAsync(acc, 0, ACC_BYTES, stream);
    hipMemsetAsync(cnt, 0, 180000ull * 4, stream);

    for (int t = 0; t < 5; t++)
        k_count<<<(E[t] + 255) / 256, 256, 0, stream>>>(ed[t], cnt + cnt_off[t], E[t]);
    k_invcnt<<<(180000 + 255) / 256, 256, 0, stream>>>(cnt, inv, 180000);

    // ---- layer 1 (fp32 sources) ----
    const float* src_l1[5] = {emb_drug, emb_gene, emb_gene, emb_dis, emb_gene};
    for (int t = 0; t < 5; t++)
        k_scatter_f32<<<(E[t] + 15) / 16, 256, 0, stream>>>(src_l1[t], es[t], ed[t],
                                                            acc + acc_off[t], E[t]);
    k_build_w<<<512, 256, 0, stream>>>(Wl, Wr, bl, 0, Wg, Wd, Ws, bg, bd, bs);

    k_gemm<false, true><<<(50000 + 63) / 64, 256, 0, stream>>>(
        acc + acc_off[0], inv + cnt_off[0], acc + acc_off[3], inv + cnt_off[3],
        acc + acc_off[4], inv + cnt_off[4], 3, emb_gene, Wg, bg, 1.0f / 3.0f,
        x1_gene, 50000);
    k_gemm<false, true><<<(20000 + 63) / 64, 256, 0, stream>>>(
        acc + acc_off[1], inv + cnt_off[1], nullptr, nullptr, nullptr, nullptr,
        1, emb_drug, Wd, bd, 1.0f, x1_drug, 20000);
    k_gemm<false, true><<<(10000 + 63) / 64, 256, 0, stream>>>(
        acc + acc_off[2], inv + cnt_off[2], nullptr, nullptr, nullptr, nullptr,
        1, emb_dis, Ws, bs, 1.0f, x1_dis, 10000);

    // ---- layer 2 (bf16 x1 sources) ----
    hipMemsetAsync(acc, 0, ACC_BYTES, stream);
    const unsigned short* src_l2[5] = {x1_drug, x1_gene, x1_gene, x1_dis, x1_gene};
    for (int t = 0; t < 5; t++)
        k_scatter_bf16<<<(E[t] + 15) / 16, 256, 0, stream>>>(src_l2[t], es[t], ed[t],
                                                             acc + acc_off[t], E[t]);
    k_build_w<<<512, 256, 0, stream>>>(Wl, Wr, bl, 1, Wg, Wd, Ws, bg, bd, bs);

    float* outp = (float*)d_out;
    k_gemm<true, false><<<(20000 + 63) / 64, 256, 0, stream>>>(
        acc + acc_off[1], inv + cnt_off[1], nullptr, nullptr, nullptr, nullptr,
        1, x1_drug, Wd, bd, 1.0f, outp, 20000);
    k_gemm<true, false><<<(10000 + 63) / 64, 256, 0, stream>>>(
        acc + acc_off[2], inv + cnt_off[2], nullptr, nullptr, nullptr, nullptr,
        1, x1_dis, Ws, bs, 1.0f, outp + 20000ull * 128, 10000);
    k_gemm<true, false><<<(50000 + 63) / 64, 256, 0, stream>>>(
        acc + acc_off[0], inv + cnt_off[0], acc + acc_off[3], inv + cnt_off[3],
        acc + acc_off[4], inv + cnt_off[4], 3, x1_gene, Wg, bg, 1.0f / 3.0f,
        outp + 30000ull * 128, 50000);
}

// Round 4
// 1395.267 us; speedup vs baseline: 13.8959x; 13.8959x over previous
//
#include <hip/hip_runtime.h>

typedef float floatx4 __attribute__((ext_vector_type(4)));
typedef short shortx8 __attribute__((ext_vector_type(8)));

struct P5 { const void* p[5]; };

__device__ __forceinline__ float bf16_to_f(unsigned short u) {
    union { unsigned int i; float f; } v;
    v.i = ((unsigned int)u) << 16;
    return v.f;
}
__device__ __forceinline__ unsigned short f_to_bf16(float f) {
    union { float f; unsigned int i; } v;
    v.f = f;
    unsigned int lsb = (v.i >> 16) & 1u;
    unsigned int r = v.i + 0x7fffu + lsb;
    return (unsigned short)(r >> 16);
}

// edge-count prefix (types 0..4) and node-count prefix
#define E_TOT 2720000
#define N_TOT 180000

// ---------------- zero cnti ----------------
__global__ __launch_bounds__(256) void k_zero(int* __restrict__ p, int n) {
    int i = blockIdx.x * 256 + threadIdx.x;
    if (i < n) p[i] = 0;
}

// ---------------- fused count over all 5 edge types ----------------
__global__ __launch_bounds__(256) void k_count_all(P5 dst, int* __restrict__ cnt) {
    const int ebase[5] = {0, 640000, 1280000, 1600000, 1920000};
    const int coff[5]  = {0, 50000, 70000, 80000, 130000};
    int g = blockIdx.x * 256 + threadIdx.x;
    if (g >= E_TOT) return;
    int t = (g < 640000) ? 0 : (g < 1280000) ? 1 : (g < 1600000) ? 2 : (g < 1920000) ? 3 : 4;
    int e = g - ebase[t];
    int d = ((const int*)dst.p[t])[e];
    atomicAdd(&cnt[coff[t] + d], 1);
}

// ---------------- per-type exclusive scan (1 wave per type) ----------------
__global__ __launch_bounds__(64) void k_scan(const int* __restrict__ cnt,
                                             int* __restrict__ rowptr,
                                             int* __restrict__ cursor,
                                             float* __restrict__ inv) {
    const int sizes[5] = {50000, 20000, 10000, 50000, 50000};
    const int offs[5]  = {0, 50000, 70000, 80000, 130000};
    const int rpo[5]   = {0, 50001, 70002, 80003, 130004};
    const int t = blockIdx.x;
    const int n = sizes[t], base = offs[t], rbase = rpo[t];
    const int lane = threadIdx.x;
    int running = 0;
    for (int chunk = 0; chunk < n; chunk += 64) {
        int i = chunk + lane;
        int c = (i < n) ? cnt[base + i] : 0;
        int v = c;
#pragma unroll
        for (int d = 1; d < 64; d <<= 1) {
            int u = __shfl_up(v, d);
            if (lane >= d) v += u;
        }
        if (i < n) {
            int excl = running + v - c;
            rowptr[rbase + i] = excl;
            cursor[base + i] = excl;
            inv[base + i] = 1.0f / (float)((c > 1) ? c : 1);
        }
        running += __shfl(v, 63);
    }
    if (lane == 0) rowptr[rbase + n] = running;
}

// ---------------- fused permute over all 5 edge types ----------------
__global__ __launch_bounds__(256) void k_permute_all(P5 src, P5 dst,
                                                     int* __restrict__ cursor,
                                                     int* __restrict__ esrc) {
    const int ebase[5] = {0, 640000, 1280000, 1600000, 1920000};
    const int esz[5]   = {640000, 640000, 320000, 320000, 800000};
    const int coff[5]  = {0, 50000, 70000, 80000, 130000};
    int g = blockIdx.x * 256 + threadIdx.x;
    if (g >= E_TOT) return;
    int t = (g < 640000) ? 0 : (g < 1280000) ? 1 : (g < 1600000) ? 2 : (g < 1920000) ? 3 : 4;
    int e = g - ebase[t];
    int d = ((const int*)dst.p[t])[e];
    int slot = atomicAdd(&cursor[coff[t] + d], 1);
    if ((unsigned)slot < (unsigned)esz[t])  // defensive: never write OOB
        esrc[ebase[t] + slot] = ((const int*)src.p[t])[e];
}

// ---------------- fused aggregate over all 5 (type,dst) segments -------------
// One wave per global dst-slot w (= mean row). Lane covers 2 columns.
template <bool SRCBF>
__global__ __launch_bounds__(256) void k_agg_all(P5 xs,
                                                 const int* __restrict__ rowptr,
                                                 const int* __restrict__ esrc,
                                                 const float* __restrict__ inv,
                                                 unsigned short* __restrict__ mean) {
    const int noff[5]  = {0, 50000, 70000, 80000, 130000};
    const int rpo[5]   = {0, 50001, 70002, 80003, 130004};
    const int ebase[5] = {0, 640000, 1280000, 1600000, 1920000};
    const int esz[5]   = {640000, 640000, 320000, 320000, 800000};
    int w = blockIdx.x * 4 + (threadIdx.x >> 6);
    if (w >= N_TOT) return;
    const int lane = threadIdx.x & 63;
    int t = (w < 50000) ? 0 : (w < 70000) ? 1 : (w < 80000) ? 2 : (w < 130000) ? 3 : 4;
    int d = w - noff[t];
    const int* rp = rowptr + rpo[t];
    int beg = rp[d];
    int end = rp[d + 1];
    // defensive clamps: stay inside this type's esrc segment
    if (beg < 0) beg = 0;
    if (end > esz[t]) end = esz[t];
    const int* ep = esrc + ebase[t];
    float s0 = 0.f, s1 = 0.f;
    int j = beg;
    if (SRCBF) {
        const unsigned short* xp = (const unsigned short*)xs.p[t] + (lane << 1);
        for (; j + 1 < end; j += 2) {
            int sA = ep[j];
            int sB = ep[j + 1];
            unsigned int pA = *(const unsigned int*)(xp + ((size_t)sA << 7));
            unsigned int pB = *(const unsigned int*)(xp + ((size_t)sB << 7));
            s0 += bf16_to_f((unsigned short)(pA & 0xffffu)) +
                  bf16_to_f((unsigned short)(pB & 0xffffu));
            s1 += bf16_to_f((unsigned short)(pA >> 16)) +
                  bf16_to_f((unsigned short)(pB >> 16));
        }
        if (j < end) {
            int sA = ep[j];
            unsigned int pA = *(const unsigned int*)(xp + ((size_t)sA << 7));
            s0 += bf16_to_f((unsigned short)(pA & 0xffffu));
            s1 += bf16_to_f((unsigned short)(pA >> 16));
        }
    } else {
        const float* xp = (const float*)xs.p[t] + (lane << 1);
        for (; j + 1 < end; j += 2) {
            int sA = ep[j];
            int sB = ep[j + 1];
            float2 vA = *(const float2*)(xp + ((size_t)sA << 7));
            float2 vB = *(const float2*)(xp + ((size_t)sB << 7));
            s0 += vA.x + vB.x;
            s1 += vA.y + vB.y;
        }
        if (j < end) {
            int sA = ep[j];
            float2 vA = *(const float2*)(xp + ((size_t)sA << 7));
            s0 += vA.x;
            s1 += vA.y;
        }
    }
    float ic = inv[w];
    unsigned int o = (unsigned int)f_to_bf16(s0 * ic) |
                     ((unsigned int)f_to_bf16(s1 * ic) << 16);
    *(unsigned int*)(mean + ((size_t)w << 7) + (lane << 1)) = o;
}

// ---------------- build stacked weights for one layer (fp32 in, bf16 out) ----
// Wt layouts (bf16, [128 n x K k] row-major):
//  gene  K=512: [Wl(e0) | Wl(e3) | Wl(e4) | Wr(e0)+Wr(e3)+Wr(e4)]
//  drug  K=256: [Wl(e1) | Wr(e1)]
//  dis   K=256: [Wl(e2) | Wr(e2)]
__global__ __launch_bounds__(256) void k_build_w(const float* __restrict__ Wl,
                                                 const float* __restrict__ Wr,
                                                 const float* __restrict__ bl,
                                                 int l,
                                                 unsigned short* __restrict__ Wg,
                                                 unsigned short* __restrict__ Wd,
                                                 unsigned short* __restrict__ Ws,
                                                 float* __restrict__ bg,
                                                 float* __restrict__ bd,
                                                 float* __restrict__ bs) {
    int t = blockIdx.x * 256 + threadIdx.x;
    if (t < 128 * 512) {
        int n = t >> 9;
        int kg = t & 511;
        int b = kg >> 7, k = kg & 127;
        float v;
        if (b == 0)
            v = Wl[(((size_t)l * 5 + 0) * 128 + n) * 128 + k];
        else if (b == 1)
            v = Wl[(((size_t)l * 5 + 3) * 128 + n) * 128 + k];
        else if (b == 2)
            v = Wl[(((size_t)l * 5 + 4) * 128 + n) * 128 + k];
        else
            v = Wr[(((size_t)l * 5 + 0) * 128 + n) * 128 + k] +
                Wr[(((size_t)l * 5 + 3) * 128 + n) * 128 + k] +
                Wr[(((size_t)l * 5 + 4) * 128 + n) * 128 + k];
        Wg[n * 512 + kg] = f_to_bf16(v);
    } else if (t < 131072) {
        int t2 = t - 65536;
        int which = (t2 >= 32768) ? 1 : 0;  // 0=drug(e1), 1=disease(e2)
        int t3 = which ? t2 - 32768 : t2;
        int n = t3 >> 8;
        int kg = t3 & 255;
        int b = kg >> 7, k = kg & 127;
        int ei = which ? 2 : 1;
        float v = (b == 0) ? Wl[(((size_t)l * 5 + ei) * 128 + n) * 128 + k]
                           : Wr[(((size_t)l * 5 + ei) * 128 + n) * 128 + k];
        (which ? Ws : Wd)[n * 256 + kg] = f_to_bf16(v);
    }
    if (t < 128) {
        int n = t;
        bg[n] = bl[((size_t)l * 5 + 0) * 128 + n] +
                bl[((size_t)l * 5 + 3) * 128 + n] +
                bl[((size_t)l * 5 + 4) * 128 + n];
        bd[n] = bl[((size_t)l * 5 + 1) * 128 + n];
        bs[n] = bl[((size_t)l * 5 + 2) * 128 + n];
    }
}

// ---------------- fused GEMM ----------------
// out[M,128] = relu( ( [mean_0|mean_1|mean_2|x] @ Wt^T + bias_sum ) * inv_k )
// block = 256 = 4 waves; each wave: 16 rows x 128 cols via 8 MFMA 16x16x32 tiles.
template <bool XBF, bool OUTBF>
__global__ __launch_bounds__(256) void k_gemm(const unsigned short* __restrict__ m0,
                                              const unsigned short* __restrict__ m1,
                                              const unsigned short* __restrict__ m2,
                                              int n_acc,
                                              const void* __restrict__ xdst,
                                              const unsigned short* __restrict__ Wt,
                                              const float* __restrict__ bias,
                                              float inv_k,
                                              void* __restrict__ out,
                                              int M) {
    const int K = (n_acc + 1) << 7;
    const int lane = threadIdx.x & 63;
    const int wave = threadIdx.x >> 6;
    const int quad = lane >> 4;
    const int l16 = lane & 15;
    const int m_base = blockIdx.x * 64 + wave * 16;
    int row = m_base + l16;
    if (row > M - 1) row = M - 1;

    floatx4 acc[8];
#pragma unroll
    for (int i = 0; i < 8; i++) acc[i] = floatx4{0.f, 0.f, 0.f, 0.f};

    for (int s = 0; s <= n_acc; s++) {
        const bool is_x = (s == n_acc);
        const unsigned short* mp = nullptr;
        if (!is_x) {
            const unsigned short* ms = (s == 0) ? m0 : (s == 1) ? m1 : m2;
            mp = ms + ((size_t)row << 7);
        }
#pragma unroll
        for (int kq = 0; kq < 4; kq++) {
            const int ko = (kq << 5) + (quad << 3);
            shortx8 afrag;
            if (!is_x) {
                afrag = *(const shortx8*)(mp + ko);
            } else if (XBF) {
                const unsigned short* xp = (const unsigned short*)xdst + ((size_t)row << 7);
                afrag = *(const shortx8*)(xp + ko);
            } else {
                const float* xp = (const float*)xdst + ((size_t)row << 7);
                floatx4 v0 = *(const floatx4*)(xp + ko);
                floatx4 v1 = *(const floatx4*)(xp + ko + 4);
                afrag[0] = (short)f_to_bf16(v0[0]);
                afrag[1] = (short)f_to_bf16(v0[1]);
                afrag[2] = (short)f_to_bf16(v0[2]);
                afrag[3] = (short)f_to_bf16(v0[3]);
                afrag[4] = (short)f_to_bf16(v1[0]);
                afrag[5] = (short)f_to_bf16(v1[1]);
                afrag[6] = (short)f_to_bf16(v1[2]);
                afrag[7] = (short)f_to_bf16(v1[3]);
            }
            const int kglob = (s << 7) + ko;
            const unsigned short* wp = Wt + (size_t)l16 * K + kglob;
#pragma unroll
            for (int nt = 0; nt < 8; nt++) {
                shortx8 bfrag = *(const shortx8*)(wp + ((size_t)(nt << 4)) * K);
                acc[nt] = __builtin_amdgcn_mfma_f32_16x16x32_bf16(afrag, bfrag, acc[nt], 0, 0, 0);
            }
        }
    }

    // epilogue: D mapping col=lane&15, row=quad*4+reg
#pragma unroll
    for (int nt = 0; nt < 8; nt++) {
        const int col = (nt << 4) + l16;
        const float b = bias[col];
#pragma unroll
        for (int r = 0; r < 4; r++) {
            const int orow = m_base + (quad << 2) + r;
            if (orow < M) {
                float v = fmaxf((acc[nt][r] + b) * inv_k, 0.f);
                if (OUTBF)
                    ((unsigned short*)out)[((size_t)orow << 7) + col] = f_to_bf16(v);
                else
                    ((float*)out)[((size_t)orow << 7) + col] = v;
            }
        }
    }
}

extern "C" void kernel_launch(void* const* d_in, const int* in_sizes, int n_in,
                              void* d_out, int out_size, void* d_ws, size_t ws_size,
                              hipStream_t stream) {
    const float* emb_drug = (const float*)d_in[0];
    const float* emb_dis  = (const float*)d_in[1];
    const float* emb_gene = (const float*)d_in[2];
    const float* Wl = (const float*)d_in[3];
    const float* Wr = (const float*)d_in[4];
    const float* bl = (const float*)d_in[5];
    P5 srcs = {{d_in[6], d_in[8], d_in[10], d_in[12], d_in[14]}};
    P5 dsts = {{d_in[7], d_in[9], d_in[11], d_in[13], d_in[15]}};

    char* base = (char*)d_ws;
    size_t off = 0;
    auto alloc = [&](size_t bytes) -> void* {
        void* r = base + off;
        off = (off + bytes + 255) & ~(size_t)255;
        return r;
    };
    int* cnti = (int*)alloc(180000ull * 4);
    int* rowptr = (int*)alloc(180005ull * 4);
    int* cursor = (int*)alloc(180000ull * 4);
    int* esrc = (int*)alloc((size_t)(E_TOT + 16) * 4);
    float* inv = (float*)alloc(180000ull * 4);
    unsigned short* mean = (unsigned short*)alloc(180000ull * 128 * 2);
    unsigned short* x1_drug = (unsigned short*)alloc(20000ull * 128 * 2);
    unsigned short* x1_dis  = (unsigned short*)alloc(10000ull * 128 * 2);
    unsigned short* x1_gene = (unsigned short*)alloc(50000ull * 128 * 2);
    unsigned short* Wg0 = (unsigned short*)alloc(128ull * 512 * 2);
    unsigned short* Wd0 = (unsigned short*)alloc(128ull * 256 * 2);
    unsigned short* Ws0 = (unsigned short*)alloc(128ull * 256 * 2);
    unsigned short* Wg1 = (unsigned short*)alloc(128ull * 512 * 2);
    unsigned short* Wd1 = (unsigned short*)alloc(128ull * 256 * 2);
    unsigned short* Ws1 = (unsigned short*)alloc(128ull * 256 * 2);
    float* bg0 = (float*)alloc(128 * 4);
    float* bd0 = (float*)alloc(128 * 4);
    float* bs0 = (float*)alloc(128 * 4);
    float* bg1 = (float*)alloc(128 * 4);
    float* bd1 = (float*)alloc(128 * 4);
    float* bs1 = (float*)alloc(128 * 4);

    // ---- CSR build (edge structure is layer-invariant) ----
    k_zero<<<(180000 + 255) / 256, 256, 0, stream>>>(cnti, 180000);
    k_count_all<<<(E_TOT + 255) / 256, 256, 0, stream>>>(dsts, cnti);
    k_scan<<<5, 64, 0, stream>>>(cnti, rowptr, cursor, inv);
    k_permute_all<<<(E_TOT + 255) / 256, 256, 0, stream>>>(srcs, dsts, cursor, esrc);

    // ---- stacked weights, both layers ----
    k_build_w<<<512, 256, 0, stream>>>(Wl, Wr, bl, 0, Wg0, Wd0, Ws0, bg0, bd0, bs0);
    k_build_w<<<512, 256, 0, stream>>>(Wl, Wr, bl, 1, Wg1, Wd1, Ws1, bg1, bd1, bs1);

    const long long MOFF1 = 50000ll * 128, MOFF2 = 70000ll * 128;
    const long long MOFF3 = 80000ll * 128, MOFF4 = 130000ll * 128;

    // ---- layer 1 ----
    P5 xs1 = {{emb_drug, emb_gene, emb_gene, emb_dis, emb_gene}};
    k_agg_all<false><<<(N_TOT + 3) / 4, 256, 0, stream>>>(xs1, rowptr, esrc, inv, mean);
    k_gemm<false, true><<<(50000 + 63) / 64, 256, 0, stream>>>(
        mean, mean + MOFF3, mean + MOFF4, 3, emb_gene, Wg0, bg0, 1.0f / 3.0f,
        x1_gene, 50000);
    k_gemm<false, true><<<(20000 + 63) / 64, 256, 0, stream>>>(
        mean + MOFF1, nullptr, nullptr, 1, emb_drug, Wd0, bd0, 1.0f, x1_drug, 20000);
    k_gemm<false, true><<<(10000 + 63) / 64, 256, 0, stream>>>(
        mean + MOFF2, nullptr, nullptr, 1, emb_dis, Ws0, bs0, 1.0f, x1_dis, 10000);

    // ---- layer 2 ----
    P5 xs2 = {{x1_drug, x1_gene, x1_gene, x1_dis, x1_gene}};
    k_agg_all<true><<<(N_TOT + 3) / 4, 256, 0, stream>>>(xs2, rowptr, esrc, inv, mean);

    float* outp = (float*)d_out;
    k_gemm<true, false><<<(20000 + 63) / 64, 256, 0, stream>>>(
        mean + MOFF1, nullptr, nullptr, 1, x1_drug, Wd1, bd1, 1.0f, outp, 20000);
    k_gemm<true, false><<<(10000 + 63) / 64, 256, 0, stream>>>(
        mean + MOFF2, nullptr, nullptr, 1, x1_dis, Ws1, bs1, 1.0f,
        outp + 20000ull * 128, 10000);
    k_gemm<true, false><<<(50000 + 63) / 64, 256, 0, stream>>>(
        mean, mean + MOFF3, mean + MOFF4, 3, x1_gene, Wg1, bg1, 1.0f / 3.0f,
        outp + 30000ull * 128, 50000);
}

// Round 5
// 974.048 us; speedup vs baseline: 19.9050x; 1.4324x over previous
//
#include <hip/hip_runtime.h>

typedef float floatx4 __attribute__((ext_vector_type(4)));
typedef short shortx8 __attribute__((ext_vector_type(8)));

struct P5 { const void* p[5]; };

__device__ __forceinline__ float bf16_to_f(unsigned short u) {
    union { unsigned int i; float f; } v;
    v.i = ((unsigned int)u) << 16;
    return v.f;
}
__device__ __forceinline__ unsigned short f_to_bf16(float f) {
    union { float f; unsigned int i; } v;
    v.f = f;
    unsigned int lsb = (v.i >> 16) & 1u;
    unsigned int r = v.i + 0x7fffu + lsb;
    return (unsigned short)(r >> 16);
}

#define E_TOT 2720000
#define N_TOT 180000
// scan blocking: 256 elements per block, blocks per type {196,79,40,196,196}
#define NBLK 707

__device__ __forceinline__ int blk_type(int b) {
    return (b < 196) ? 0 : (b < 275) ? 1 : (b < 315) ? 2 : (b < 511) ? 3 : 4;
}

// ---------------- zero cnti ----------------
__global__ __launch_bounds__(256) void k_zero(int* __restrict__ p, int n) {
    int i = blockIdx.x * 256 + threadIdx.x;
    if (i < n) p[i] = 0;
}

// ---------------- fused count over all 5 edge types ----------------
__global__ __launch_bounds__(256) void k_count_all(P5 dst, int* __restrict__ cnt) {
    const int ebase[5] = {0, 640000, 1280000, 1600000, 1920000};
    const int coff[5]  = {0, 50000, 70000, 80000, 130000};
    int g = blockIdx.x * 256 + threadIdx.x;
    if (g >= E_TOT) return;
    int t = (g < 640000) ? 0 : (g < 1280000) ? 1 : (g < 1600000) ? 2 : (g < 1920000) ? 3 : 4;
    int e = g - ebase[t];
    int d = ((const int*)dst.p[t])[e];
    atomicAdd(&cnt[coff[t] + d], 1);
}

// ---------------- scan stage 1: per-block sums ----------------
__global__ __launch_bounds__(256) void k_scan1(const int* __restrict__ cnt,
                                               int* __restrict__ bsum) {
    const int sizes[5] = {50000, 20000, 10000, 50000, 50000};
    const int offs[5]  = {0, 50000, 70000, 80000, 130000};
    const int bbase[5] = {0, 196, 275, 315, 511};
    int b = blockIdx.x;
    int t = blk_type(b);
    int i = (b - bbase[t]) * 256 + threadIdx.x;
    int c = (i < sizes[t]) ? cnt[offs[t] + i] : 0;
    int v = c;
    int lane = threadIdx.x & 63;
    int wave = threadIdx.x >> 6;
#pragma unroll
    for (int d = 1; d < 64; d <<= 1) v += __shfl_xor(v, d);
    __shared__ int ws[4];
    if (lane == 0) ws[wave] = v;
    __syncthreads();
    if (threadIdx.x == 0) bsum[b] = ws[0] + ws[1] + ws[2] + ws[3];
}

// ---------------- scan stage 2: per-type scan of block sums ----------------
// grid = 5 blocks x 64 threads; writes exclusive block offsets + type totals.
__global__ __launch_bounds__(64) void k_scan2(const int* __restrict__ bsum,
                                              int* __restrict__ boff,
                                              int* __restrict__ rowptr) {
    const int sizes[5] = {50000, 20000, 10000, 50000, 50000};
    const int nblk[5]  = {196, 79, 40, 196, 196};
    const int bbase[5] = {0, 196, 275, 315, 511};
    const int rpo[5]   = {0, 50001, 70002, 80003, 130004};
    int t = blockIdx.x;
    int lane = threadIdx.x;
    int n = nblk[t];
    int running = 0;
    for (int chunk = 0; chunk < n; chunk += 64) {
        int i = chunk + lane;
        int c = (i < n) ? bsum[bbase[t] + i] : 0;
        int v = c;
#pragma unroll
        for (int d = 1; d < 64; d <<= 1) {
            int u = __shfl_up(v, d);
            if (lane >= d) v += u;
        }
        if (i < n) boff[bbase[t] + i] = running + v - c;
        running += __shfl(v, 63);
    }
    if (lane == 0) rowptr[rpo[t] + sizes[t]] = running;
}

// ---------------- scan stage 3: in-block exclusive scan + block offset -------
__global__ __launch_bounds__(256) void k_scan3(const int* __restrict__ cnt,
                                               const int* __restrict__ boff,
                                               int* __restrict__ rowptr,
                                               int* __restrict__ cursor,
                                               float* __restrict__ inv) {
    const int sizes[5] = {50000, 20000, 10000, 50000, 50000};
    const int offs[5]  = {0, 50000, 70000, 80000, 130000};
    const int bbase[5] = {0, 196, 275, 315, 511};
    const int rpo[5]   = {0, 50001, 70002, 80003, 130004};
    int b = blockIdx.x;
    int t = blk_type(b);
    int i = (b - bbase[t]) * 256 + threadIdx.x;
    int lane = threadIdx.x & 63;
    int wave = threadIdx.x >> 6;
    int c = (i < sizes[t]) ? cnt[offs[t] + i] : 0;
    int v = c;
#pragma unroll
    for (int d = 1; d < 64; d <<= 1) {
        int u = __shfl_up(v, d);
        if (lane >= d) v += u;
    }
    __shared__ int ws[4];
    if (lane == 63) ws[wave] = v;
    __syncthreads();
    int woff = 0;
    for (int wv = 0; wv < wave; wv++) woff += ws[wv];
    if (i < sizes[t]) {
        int excl = boff[b] + woff + v - c;
        rowptr[rpo[t] + i] = excl;
        cursor[offs[t] + i] = excl;
        inv[offs[t] + i] = 1.0f / (float)((c > 1) ? c : 1);
    }
}

// ---------------- fused permute over all 5 edge types ----------------
__global__ __launch_bounds__(256) void k_permute_all(P5 src, P5 dst,
                                                     int* __restrict__ cursor,
                                                     int* __restrict__ esrc) {
    const int ebase[5] = {0, 640000, 1280000, 1600000, 1920000};
    const int esz[5]   = {640000, 640000, 320000, 320000, 800000};
    const int coff[5]  = {0, 50000, 70000, 80000, 130000};
    int g = blockIdx.x * 256 + threadIdx.x;
    if (g >= E_TOT) return;
    int t = (g < 640000) ? 0 : (g < 1280000) ? 1 : (g < 1600000) ? 2 : (g < 1920000) ? 3 : 4;
    int e = g - ebase[t];
    int d = ((const int*)dst.p[t])[e];
    int slot = atomicAdd(&cursor[coff[t] + d], 1);
    if ((unsigned)slot < (unsigned)esz[t])  // defensive: never write OOB
        esrc[ebase[t] + slot] = ((const int*)src.p[t])[e];
}

// ---------------- cast fp32 -> bf16 (rows x 128) ----------------
__global__ __launch_bounds__(256) void k_cast(const float* __restrict__ x,
                                              unsigned short* __restrict__ o,
                                              int nelem) {
    int i = (blockIdx.x * 256 + threadIdx.x) * 4;
    if (i >= nelem) return;
    floatx4 v = *(const floatx4*)(x + i);
    ushort4 r;
    r.x = f_to_bf16(v[0]);
    r.y = f_to_bf16(v[1]);
    r.z = f_to_bf16(v[2]);
    r.w = f_to_bf16(v[3]);
    *(ushort4*)(o + i) = r;
}

// ---------------- fused aggregate over all 5 (type,dst) segments -------------
// One wave per global dst-slot w (= mean row). Lane covers 2 columns. bf16 src.
__global__ __launch_bounds__(256) void k_agg_all(P5 xs,
                                                 const int* __restrict__ rowptr,
                                                 const int* __restrict__ esrc,
                                                 const float* __restrict__ inv,
                                                 unsigned short* __restrict__ mean) {
    const int noff[5]  = {0, 50000, 70000, 80000, 130000};
    const int rpo[5]   = {0, 50001, 70002, 80003, 130004};
    const int ebase[5] = {0, 640000, 1280000, 1600000, 1920000};
    const int esz[5]   = {640000, 640000, 320000, 320000, 800000};
    int w = blockIdx.x * 4 + (threadIdx.x >> 6);
    if (w >= N_TOT) return;
    const int lane = threadIdx.x & 63;
    int t = (w < 50000) ? 0 : (w < 70000) ? 1 : (w < 80000) ? 2 : (w < 130000) ? 3 : 4;
    int d = w - noff[t];
    const int* rp = rowptr + rpo[t];
    int beg = rp[d];
    int end = rp[d + 1];
    if (beg < 0) beg = 0;
    if (end > esz[t]) end = esz[t];
    const int* ep = esrc + ebase[t];
    float s0 = 0.f, s1 = 0.f;
    int j = beg;
    const unsigned short* xp = (const unsigned short*)xs.p[t] + (lane << 1);
    for (; j + 1 < end; j += 2) {
        int sA = ep[j];
        int sB = ep[j + 1];
        unsigned int pA = *(const unsigned int*)(xp + ((size_t)sA << 7));
        unsigned int pB = *(const unsigned int*)(xp + ((size_t)sB << 7));
        s0 += bf16_to_f((unsigned short)(pA & 0xffffu)) +
              bf16_to_f((unsigned short)(pB & 0xffffu));
        s1 += bf16_to_f((unsigned short)(pA >> 16)) +
              bf16_to_f((unsigned short)(pB >> 16));
    }
    if (j < end) {
        int sA = ep[j];
        unsigned int pA = *(const unsigned int*)(xp + ((size_t)sA << 7));
        s0 += bf16_to_f((unsigned short)(pA & 0xffffu));
        s1 += bf16_to_f((unsigned short)(pA >> 16));
    }
    float ic = inv[w];
    unsigned int o = (unsigned int)f_to_bf16(s0 * ic) |
                     ((unsigned int)f_to_bf16(s1 * ic) << 16);
    *(unsigned int*)(mean + ((size_t)w << 7) + (lane << 1)) = o;
}

// ---------------- build stacked weights for one layer (fp32 in, bf16 out) ----
// Wt layouts (bf16, [128 n x K k] row-major):
//  gene  K=512: [Wl(e0) | Wl(e3) | Wl(e4) | Wr(e0)+Wr(e3)+Wr(e4)]
//  drug  K=256: [Wl(e1) | Wr(e1)]
//  dis   K=256: [Wl(e2) | Wr(e2)]
__global__ __launch_bounds__(256) void k_build_w(const float* __restrict__ Wl,
                                                 const float* __restrict__ Wr,
                                                 const float* __restrict__ bl,
                                                 int l,
                                                 unsigned short* __restrict__ Wg,
                                                 unsigned short* __restrict__ Wd,
                                                 unsigned short* __restrict__ Ws,
                                                 float* __restrict__ bg,
                                                 float* __restrict__ bd,
                                                 float* __restrict__ bs) {
    int t = blockIdx.x * 256 + threadIdx.x;
    if (t < 128 * 512) {
        int n = t >> 9;
        int kg = t & 511;
        int b = kg >> 7, k = kg & 127;
        float v;
        if (b == 0)
            v = Wl[(((size_t)l * 5 + 0) * 128 + n) * 128 + k];
        else if (b == 1)
            v = Wl[(((size_t)l * 5 + 3) * 128 + n) * 128 + k];
        else if (b == 2)
            v = Wl[(((size_t)l * 5 + 4) * 128 + n) * 128 + k];
        else
            v = Wr[(((size_t)l * 5 + 0) * 128 + n) * 128 + k] +
                Wr[(((size_t)l * 5 + 3) * 128 + n) * 128 + k] +
                Wr[(((size_t)l * 5 + 4) * 128 + n) * 128 + k];
        Wg[n * 512 + kg] = f_to_bf16(v);
    } else if (t < 131072) {
        int t2 = t - 65536;
        int which = (t2 >= 32768) ? 1 : 0;  // 0=drug(e1), 1=disease(e2)
        int t3 = which ? t2 - 32768 : t2;
        int n = t3 >> 8;
        int kg = t3 & 255;
        int b = kg >> 7, k = kg & 127;
        int ei = which ? 2 : 1;
        float v = (b == 0) ? Wl[(((size_t)l * 5 + ei) * 128 + n) * 128 + k]
                           : Wr[(((size_t)l * 5 + ei) * 128 + n) * 128 + k];
        (which ? Ws : Wd)[n * 256 + kg] = f_to_bf16(v);
    }
    if (t < 128) {
        int n = t;
        bg[n] = bl[((size_t)l * 5 + 0) * 128 + n] +
                bl[((size_t)l * 5 + 3) * 128 + n] +
                bl[((size_t)l * 5 + 4) * 128 + n];
        bd[n] = bl[((size_t)l * 5 + 1) * 128 + n];
        bs[n] = bl[((size_t)l * 5 + 2) * 128 + n];
    }
}

// ---------------- fused GEMM ----------------
// out[M,128] = relu( ( [mean_0|mean_1|mean_2|x] @ Wt^T + bias_sum ) * inv_k )
// block = 256 = 4 waves; each wave: 16 rows x 128 cols via 8 MFMA 16x16x32 tiles.
// All A-operands bf16. OUTBF: out bf16 (else fp32).
template <bool OUTBF>
__global__ __launch_bounds__(256) void k_gemm(const unsigned short* __restrict__ m0,
                                              const unsigned short* __restrict__ m1,
                                              const unsigned short* __restrict__ m2,
                                              int n_acc,
                                              const unsigned short* __restrict__ xdst,
                                              const unsigned short* __restrict__ Wt,
                                              const float* __restrict__ bias,
                                              float inv_k,
                                              void* __restrict__ out,
                                              int M) {
    const int K = (n_acc + 1) << 7;
    const int lane = threadIdx.x & 63;
    const int wave = threadIdx.x >> 6;
    const int quad = lane >> 4;
    const int l16 = lane & 15;
    const int m_base = blockIdx.x * 64 + wave * 16;
    int row = m_base + l16;
    if (row > M - 1) row = M - 1;

    floatx4 acc[8];
#pragma unroll
    for (int i = 0; i < 8; i++) acc[i] = floatx4{0.f, 0.f, 0.f, 0.f};

    for (int s = 0; s <= n_acc; s++) {
        const unsigned short* mp =
            ((s == n_acc) ? xdst : (s == 0) ? m0 : (s == 1) ? m1 : m2) + ((size_t)row << 7);
#pragma unroll
        for (int kq = 0; kq < 4; kq++) {
            const int ko = (kq << 5) + (quad << 3);
            shortx8 afrag = *(const shortx8*)(mp + ko);
            const int kglob = (s << 7) + ko;
            const unsigned short* wp = Wt + (size_t)l16 * K + kglob;
#pragma unroll
            for (int nt = 0; nt < 8; nt++) {
                shortx8 bfrag = *(const shortx8*)(wp + ((size_t)(nt << 4)) * K);
                acc[nt] = __builtin_amdgcn_mfma_f32_16x16x32_bf16(afrag, bfrag, acc[nt], 0, 0, 0);
            }
        }
    }

    // epilogue: D mapping col=lane&15, row=quad*4+reg
#pragma unroll
    for (int nt = 0; nt < 8; nt++) {
        const int col = (nt << 4) + l16;
        const float b = bias[col];
#pragma unroll
        for (int r = 0; r < 4; r++) {
            const int orow = m_base + (quad << 2) + r;
            if (orow < M) {
                float v = fmaxf((acc[nt][r] + b) * inv_k, 0.f);
                if (OUTBF)
                    ((unsigned short*)out)[((size_t)orow << 7) + col] = f_to_bf16(v);
                else
                    ((float*)out)[((size_t)orow << 7) + col] = v;
            }
        }
    }
}

extern "C" void kernel_launch(void* const* d_in, const int* in_sizes, int n_in,
                              void* d_out, int out_size, void* d_ws, size_t ws_size,
                              hipStream_t stream) {
    const float* emb_drug = (const float*)d_in[0];
    const float* emb_dis  = (const float*)d_in[1];
    const float* emb_gene = (const float*)d_in[2];
    const float* Wl = (const float*)d_in[3];
    const float* Wr = (const float*)d_in[4];
    const float* bl = (const float*)d_in[5];
    P5 srcs = {{d_in[6], d_in[8], d_in[10], d_in[12], d_in[14]}};
    P5 dsts = {{d_in[7], d_in[9], d_in[11], d_in[13], d_in[15]}};

    char* base = (char*)d_ws;
    size_t off = 0;
    auto alloc = [&](size_t bytes) -> void* {
        void* r = base + off;
        off = (off + bytes + 255) & ~(size_t)255;
        return r;
    };
    int* cnti = (int*)alloc(180000ull * 4);
    int* rowptr = (int*)alloc(180005ull * 4);
    int* cursor = (int*)alloc(180000ull * 4);
    int* bsum = (int*)alloc((size_t)NBLK * 4);
    int* boff = (int*)alloc((size_t)NBLK * 4);
    int* esrc = (int*)alloc((size_t)(E_TOT + 16) * 4);
    float* inv = (float*)alloc(180000ull * 4);
    unsigned short* mean = (unsigned short*)alloc(180000ull * 128 * 2);
    unsigned short* xb_drug = (unsigned short*)alloc(20000ull * 128 * 2);
    unsigned short* xb_dis  = (unsigned short*)alloc(10000ull * 128 * 2);
    unsigned short* xb_gene = (unsigned short*)alloc(50000ull * 128 * 2);
    unsigned short* x1_drug = (unsigned short*)alloc(20000ull * 128 * 2);
    unsigned short* x1_dis  = (unsigned short*)alloc(10000ull * 128 * 2);
    unsigned short* x1_gene = (unsigned short*)alloc(50000ull * 128 * 2);
    unsigned short* Wg0 = (unsigned short*)alloc(128ull * 512 * 2);
    unsigned short* Wd0 = (unsigned short*)alloc(128ull * 256 * 2);
    unsigned short* Ws0 = (unsigned short*)alloc(128ull * 256 * 2);
    unsigned short* Wg1 = (unsigned short*)alloc(128ull * 512 * 2);
    unsigned short* Wd1 = (unsigned short*)alloc(128ull * 256 * 2);
    unsigned short* Ws1 = (unsigned short*)alloc(128ull * 256 * 2);
    float* bg0 = (float*)alloc(128 * 4);
    float* bd0 = (float*)alloc(128 * 4);
    float* bs0 = (float*)alloc(128 * 4);
    float* bg1 = (float*)alloc(128 * 4);
    float* bd1 = (float*)alloc(128 * 4);
    float* bs1 = (float*)alloc(128 * 4);

    // ---- CSR build (edge structure is layer-invariant) ----
    k_zero<<<(180000 + 255) / 256, 256, 0, stream>>>(cnti, 180000);
    k_count_all<<<(E_TOT + 255) / 256, 256, 0, stream>>>(dsts, cnti);
    k_scan1<<<NBLK, 256, 0, stream>>>(cnti, bsum);
    k_scan2<<<5, 64, 0, stream>>>(bsum, boff, rowptr);
    k_scan3<<<NBLK, 256, 0, stream>>>(cnti, boff, rowptr, cursor, inv);
    k_permute_all<<<(E_TOT + 255) / 256, 256, 0, stream>>>(srcs, dsts, cursor, esrc);

    // ---- bf16 copies of embeddings ----
    k_cast<<<(20000 * 128 / 4 + 255) / 256, 256, 0, stream>>>(emb_drug, xb_drug, 20000 * 128);
    k_cast<<<(10000 * 128 / 4 + 255) / 256, 256, 0, stream>>>(emb_dis, xb_dis, 10000 * 128);
    k_cast<<<(50000 * 128 / 4 + 255) / 256, 256, 0, stream>>>(emb_gene, xb_gene, 50000 * 128);

    // ---- stacked weights, both layers ----
    k_build_w<<<512, 256, 0, stream>>>(Wl, Wr, bl, 0, Wg0, Wd0, Ws0, bg0, bd0, bs0);
    k_build_w<<<512, 256, 0, stream>>>(Wl, Wr, bl, 1, Wg1, Wd1, Ws1, bg1, bd1, bs1);

    const long long MOFF1 = 50000ll * 128, MOFF2 = 70000ll * 128;
    const long long MOFF3 = 80000ll * 128, MOFF4 = 130000ll * 128;

    // ---- layer 1 (bf16 sources) ----
    P5 xs1 = {{xb_drug, xb_gene, xb_gene, xb_dis, xb_gene}};
    k_agg_all<<<(N_TOT + 3) / 4, 256, 0, stream>>>(xs1, rowptr, esrc, inv, mean);
    k_gemm<true><<<(50000 + 63) / 64, 256, 0, stream>>>(
        mean, mean + MOFF3, mean + MOFF4, 3, xb_gene, Wg0, bg0, 1.0f / 3.0f,
        x1_gene, 50000);
    k_gemm<true><<<(20000 + 63) / 64, 256, 0, stream>>>(
        mean + MOFF1, nullptr, nullptr, 1, xb_drug, Wd0, bd0, 1.0f, x1_drug, 20000);
    k_gemm<true><<<(10000 + 63) / 64, 256, 0, stream>>>(
        mean + MOFF2, nullptr, nullptr, 1, xb_dis, Ws0, bs0, 1.0f, x1_dis, 10000);

    // ---- layer 2 ----
    P5 xs2 = {{x1_drug, x1_gene, x1_gene, x1_dis, x1_gene}};
    k_agg_all<<<(N_TOT + 3) / 4, 256, 0, stream>>>(xs2, rowptr, esrc, inv, mean);

    float* outp = (float*)d_out;
    k_gemm<false><<<(20000 + 63) / 64, 256, 0, stream>>>(
        mean + MOFF1, nullptr, nullptr, 1, x1_drug, Wd1, bd1, 1.0f, outp, 20000);
    k_gemm<false><<<(10000 + 63) / 64, 256, 0, stream>>>(
        mean + MOFF2, nullptr, nullptr, 1, x1_dis, Ws1, bs1, 1.0f,
        outp + 20000ull * 128, 10000);
    k_gemm<false><<<(50000 + 63) / 64, 256, 0, stream>>>(
        mean, mean + MOFF3, mean + MOFF4, 3, x1_gene, Wg1, bg1, 1.0f / 3.0f,
        outp + 30000ull * 128, 50000);
}